// Round 17
// baseline (218.450 us; speedup 1.0000x reference)
//
#include <hip/hip_runtime.h>
#include <hip/hip_bf16.h>
#include <stdint.h>

#define T_TOK 2048
#define HD    1024
#define ID    4096
#define NE    8
#define NN2   8192   // 2*ID
#define CHUNK 256    // T_TOK / NE

typedef short          bf16x8 __attribute__((ext_vector_type(8)));
typedef float          f32x4  __attribute__((ext_vector_type(4)));
typedef unsigned short u16;
typedef u16            u16x4 __attribute__((ext_vector_type(4)));

__device__ __forceinline__ u16 f2bf(float f) {
    return __builtin_bit_cast(u16, __float2bfloat16(f));
}

// Barrier that does NOT drain vmcnt: LDS-ordering only (T3/T4 pattern).
__device__ __forceinline__ void lgkm_bar() {
    asm volatile("s_waitcnt lgkmcnt(0)" ::: "memory");
    __builtin_amdgcn_s_barrier();
}

// ---------------------------------------------------------------- router ----
__global__ __launch_bounds__(256) void k_router(
    const float* __restrict__ x, const float* __restrict__ rw,
    float* __restrict__ scoresT, u16* __restrict__ xbf, u16* __restrict__ xsbf)
{
    const int t   = blockIdx.x;
    const int tid = threadIdx.x;
    __shared__ float wred[NE][4];
    __shared__ float ssc;

    float4 xv = reinterpret_cast<const float4*>(x + (size_t)t * HD)[tid];
    float p[NE];
#pragma unroll
    for (int e = 0; e < NE; ++e) p[e] = 0.f;
    const float* wrow = rw + (size_t)tid * 4 * NE;
    float xj[4] = {xv.x, xv.y, xv.z, xv.w};
#pragma unroll
    for (int j = 0; j < 4; ++j)
#pragma unroll
        for (int e = 0; e < NE; ++e) p[e] += xj[j] * wrow[j * NE + e];

#pragma unroll
    for (int e = 0; e < NE; ++e) {
        float v = p[e];
#pragma unroll
        for (int o = 32; o > 0; o >>= 1) v += __shfl_down(v, o, 64);
        if ((tid & 63) == 0) wred[e][tid >> 6] = v;
    }
    __syncthreads();
    if (tid == 0) {
        float mx = -3.4e38f; int am = 0;
        float lg[NE];
#pragma unroll
        for (int e = 0; e < NE; ++e) {
            lg[e] = wred[e][0] + wred[e][1] + wred[e][2] + wred[e][3];
            if (lg[e] > mx) { mx = lg[e]; am = e; }
        }
        float sc = 1.f / (1.f + __expf(-mx));
        ssc = sc;
#pragma unroll
        for (int e = 0; e < NE; ++e)
            scoresT[(size_t)e * T_TOK + t] = (e == am) ? sc : 0.f;
    }
    __syncthreads();
    const float sc = ssc;
    ushort4 a, b;
    a.x = f2bf(xj[0]); a.y = f2bf(xj[1]); a.z = f2bf(xj[2]); a.w = f2bf(xj[3]);
    b.x = f2bf(xj[0] * sc); b.y = f2bf(xj[1] * sc); b.z = f2bf(xj[2] * sc); b.w = f2bf(xj[3] * sc);
    reinterpret_cast<ushort4*>(xbf  + (size_t)t * HD)[tid] = a;
    reinterpret_cast<ushort4*>(xsbf + (size_t)t * HD)[tid] = b;
}

// ------------------------------------------------------------------- G1 -----
// r16 pipeline; ONE delta: B fetches vectorized to dwordx4 along N
// (4 cols/thread, 4 k-rows), in-register 4x4 transpose, b64 LDS writes.
// Staging split across thread-halves (gate/up). VMEM instr 20 -> 8 /thread/step.
// Read swizzle becomes (col>>2)&3 to match the write layout (2-way reads).
__global__ __launch_bounds__(512, 2) void k_gemm1(
    const u16* __restrict__ xbf, const u16* __restrict__ xsbf,
    const float* __restrict__ sgw, const float* __restrict__ suw,
    const float* __restrict__ gup, u16* __restrict__ h2)
{
    constexpr int BM = 256, BN = 128, BK = 32, NS = HD / BK;   // 32 steps
    const int d = blockIdx.x;
    int mt, nt;
    if (d < 256) { const int r = d & 7, q = d >> 3; nt = r + 8 * (q & 3); mt = q >> 2; }
    else         { const int e = d - 256;           mt = e & 7; nt = 32 + (e >> 3); }
    const int m0 = mt * BM, n0 = nt * BN;

    const u16* A; const float* Bg; const float* Bu; int ldb;
    if (n0 < ID) { A = xbf; Bg = sgw + n0; Bu = suw + n0; ldb = ID; }
    else {
        A = xsbf;
        Bg = gup + (size_t)mt * HD * NN2 + (n0 - ID);
        Bu = Bg + ID;
        ldb = NN2;
    }

    __shared__ u16 Bgs[2][BN * BK];
    __shared__ u16 Bus[2][BN * BK];

    const int tid  = threadIdx.x;
    const int lane = tid & 63, wid = tid >> 6;
    const int wr = wid >> 1, wc = wid & 1;        // 4 x 2 wave grid
    const int lrow = lane & 15, kg = lane >> 4;

    f32x4 accg[4][4], accu[4][4];
#pragma unroll
    for (int i = 0; i < 4; ++i)
#pragma unroll
        for (int j = 0; j < 4; ++j)
#pragma unroll
            for (int r = 0; r < 4; ++r) { accg[i][j][r] = 0.f; accu[i][j][r] = 0.f; }

    // B staging: threads 0..255 stage gate, 256..511 stage up.
    // Thread: col-quad c4 (0..31), k-quad kq (0..7): 4 dwordx4 loads
    // (4 k-rows x 4 cols), reg transpose, 4 b64 LDS writes.
    const int half = tid >> 8;
    const int wt   = tid & 255;
    const int c4   = wt & 31;
    const int kq   = wt >> 5;
    const float* Bsel = half ? Bu : Bg;
    char* sb0 = half ? (char*)Bus[0] : (char*)Bgs[0];
    char* sb1 = half ? (char*)Bus[1] : (char*)Bgs[1];
    const u16* aBase = A + (size_t)(m0 + wr * 64 + lrow) * HD + kg * 8;

    f32x4 rB0[4], rB1[4];
    bf16x8 aF0[4], aF1[4];

#define LOADB(ks, R) do {                                                       \
        const float* p_ = Bsel + (size_t)((ks) * BK + kq * 4) * ldb + 4 * c4;   \
        _Pragma("unroll")                                                       \
        for (int r = 0; r < 4; ++r)                                             \
            R[r] = __builtin_nontemporal_load(                                  \
                reinterpret_cast<const f32x4*>(p_ + (size_t)r * ldb));          \
    } while (0)

#define STOREB(sbp, R) do {                                                     \
        _Pragma("unroll")                                                       \
        for (int j = 0; j < 4; ++j) {                                           \
            u16x4 q_;                                                           \
            q_[0] = f2bf(R[0][j]); q_[1] = f2bf(R[1][j]);                       \
            q_[2] = f2bf(R[2][j]); q_[3] = f2bf(R[3][j]);                       \
            const int c_ = 4 * c4 + j;                                          \
            *reinterpret_cast<u16x4*>(sbp + c_ * 64                             \
                + (((kq >> 1) ^ (c4 & 3)) * 16) + ((kq & 1) * 8)) = q_;         \
        }                                                                       \
    } while (0)

#define LOADA(ks, F) do {                                                       \
        _Pragma("unroll")                                                       \
        for (int mf = 0; mf < 4; ++mf)                                          \
            F[mf] = *reinterpret_cast<const bf16x8*>(                           \
                aBase + (size_t)mf * 16 * HD + (ks) * BK);                      \
    } while (0)

#define MFMAPH(b, F) do {                                                       \
        const char* gs_ = (const char*)Bgs[b];                                  \
        const char* us_ = (const char*)Bus[b];                                  \
        bf16x8 bgf_[4], buf_[4];                                                \
        _Pragma("unroll")                                                       \
        for (int nf = 0; nf < 4; ++nf) {                                        \
            const int col_ = wc * 64 + nf * 16 + lrow;                          \
            const int so_  = col_ * 64 + ((kg ^ ((col_ >> 2) & 3)) * 16);       \
            bgf_[nf] = *reinterpret_cast<const bf16x8*>(gs_ + so_);             \
            buf_[nf] = *reinterpret_cast<const bf16x8*>(us_ + so_);             \
        }                                                                       \
        _Pragma("unroll")                                                       \
        for (int mf = 0; mf < 4; ++mf)                                          \
            _Pragma("unroll")                                                   \
            for (int nf = 0; nf < 4; ++nf) {                                    \
                accg[mf][nf] = __builtin_amdgcn_mfma_f32_16x16x32_bf16(         \
                    F[mf], bgf_[nf], accg[mf][nf], 0, 0, 0);                    \
                accu[mf][nf] = __builtin_amdgcn_mfma_f32_16x16x32_bf16(         \
                    F[mf], buf_[nf], accu[mf][nf], 0, 0, 0);                    \
            }                                                                   \
    } while (0)

    // prologue
    LOADB(0, rB0);
    LOADB(1, rB1);
    LOADA(0, aF0);
    STOREB(sb0, rB0);
    lgkm_bar();

    for (int j = 0; j < NS / 2; ++j) {
        const int ks = 2 * j;
        // even step: compute tile ks (LDS buf0, aF0)
        {
            const int ka = (ks + 1 < NS) ? ks + 1 : NS - 1;
            const int kb = (ks + 2 < NS) ? ks + 2 : NS - 1;
            LOADA(ka, aF1);
            LOADB(kb, rB0);
        }
        MFMAPH(0, aF0);
        STOREB(sb1, rB1);
        lgkm_bar();
        // odd step: compute tile ks+1 (LDS buf1, aF1)
        {
            const int ka = (ks + 2 < NS) ? ks + 2 : NS - 1;
            const int kb = (ks + 3 < NS) ? ks + 3 : NS - 1;
            LOADA(ka, aF0);
            LOADB(kb, rB1);
        }
        MFMAPH(1, aF1);
        STOREB(sb0, rB0);
        lgkm_bar();
    }
#undef LOADB
#undef STOREB
#undef LOADA
#undef MFMAPH

    // SwiGLU epilogue -> bf16 H2
#pragma unroll
    for (int mf = 0; mf < 4; ++mf)
#pragma unroll
        for (int nf = 0; nf < 4; ++nf) {
            const int col = n0 + wc * 64 + nf * 16 + lrow;
#pragma unroll
            for (int r = 0; r < 4; ++r) {
                const int row = m0 + wr * 64 + mf * 16 + kg * 4 + r;
                const float g = accg[mf][nf][r];
                const float u = accu[mf][nf][r];
                const float h = (g / (1.f + __expf(-g))) * u;
                h2[(size_t)row * NN2 + col] = f2bf(h);
            }
        }
}

// ------------------------------------------------------------------- G2 -----
// r16 pipeline; ONE delta: B fetches vectorized to dwordx4 along N
// (4 cols/thread, 4 k-rows), reg transpose, b64 LDS writes. Read swizzle
// (col&7) UNCHANGED. VMEM instr 24 -> 12 /thread/step.
__global__ __launch_bounds__(512, 1) void k_gemm2(
    const u16* __restrict__ h2, const float* __restrict__ sdw,
    const float* __restrict__ dwn, float* __restrict__ out)
{
    constexpr int BM = 256, BN = 64, BK = 64, NS = 2048 / BK;  // 32 steps/waveset
    const int d   = blockIdx.x;               // 256 blocks
    const int mt  = d & 7;                    // = XCD
    const int q   = d >> 3;
    const int kh  = q & 1;                    // K-half: 0=sdw, 1=dwn[mt]
    const int nt  = q >> 1;                   // 0..15
    const int m0 = mt * BM, n0 = nt * BN;

    const int tid = threadIdx.x;
    const int ws  = tid >> 8;                 // waveset 0/1
    const int wt  = tid & 255;
    const int lane = wt & 63, wid4 = wt >> 6; // 4 waves per waveset
    const int wr = wid4;                      // 4x1 wave grid, 64 rows each
    const int lrow = lane & 15, kg = lane >> 4;

    __shared__ char smem[65536];              // 32 KB staging, reused as reduce
    u16*   BsBase = (u16*)smem;               // [set][buf][BN*BK]
    float* red    = (float*)smem;             // 256 x 64 f32

    f32x4 acc[4][4];
#pragma unroll
    for (int i = 0; i < 4; ++i)
#pragma unroll
        for (int j = 0; j < 4; ++j)
#pragma unroll
            for (int r = 0; r < 4; ++r) acc[i][j][r] = 0.f;

    const float* Bbase = kh ? (dwn + (size_t)mt * ID * HD + (size_t)(ws * 2048) * HD)
                            : (sdw + (size_t)(ws * 2048) * HD);
    const u16* aBase = h2 + (size_t)(m0 + wr * 64 + lrow) * NN2
                          + (size_t)kh * ID + (size_t)ws * 2048 + kg * 8;

    // B staging: col-quad c4 (0..15), k-quad kq (0..15)
    const int c4 = wt & 15;
    const int kq = wt >> 4;

    f32x4 rb0[4], rb1[4];
    bf16x8 aF0[8], aF1[8];

#define LOADB2(ks, R) do {                                                      \
        const float* p_ = Bbase + (size_t)((ks) * BK + kq * 4) * HD + n0 + 4 * c4; \
        _Pragma("unroll")                                                       \
        for (int r = 0; r < 4; ++r)                                             \
            R[r] = *reinterpret_cast<const f32x4*>(p_ + (size_t)r * HD);        \
    } while (0)

#define STOREB2(b, R) do {                                                      \
        char* bs_ = (char*)(BsBase + (size_t)(ws * 2 + (b)) * BN * BK);         \
        _Pragma("unroll")                                                       \
        for (int j = 0; j < 4; ++j) {                                           \
            u16x4 q_;                                                           \
            q_[0] = f2bf(R[0][j]); q_[1] = f2bf(R[1][j]);                       \
            q_[2] = f2bf(R[2][j]); q_[3] = f2bf(R[3][j]);                       \
            const int c_ = 4 * c4 + j;                                          \
            *reinterpret_cast<u16x4*>(bs_ + c_ * 128                            \
                + (((kq >> 1) ^ (c_ & 7)) * 16) + ((kq & 1) * 8)) = q_;         \
        }                                                                       \
    } while (0)

#define LOADA2(ks, F) do {                                                      \
        _Pragma("unroll")                                                       \
        for (int mf = 0; mf < 4; ++mf)                                          \
            _Pragma("unroll")                                                   \
            for (int kk = 0; kk < 2; ++kk)                                      \
                F[mf * 2 + kk] = *reinterpret_cast<const bf16x8*>(              \
                    aBase + (size_t)mf * 16 * NN2 + (ks) * BK + kk * 32);       \
    } while (0)

#define MFMAPH2(b, F) do {                                                      \
        const char* bs_ = (const char*)(BsBase + (size_t)(ws * 2 + (b)) * BN * BK); \
        _Pragma("unroll")                                                       \
        for (int kk = 0; kk < 2; ++kk) {                                        \
            bf16x8 bf_[4];                                                      \
            _Pragma("unroll")                                                   \
            for (int nf = 0; nf < 4; ++nf) {                                    \
                const int col_ = nf * 16 + lrow;                                \
                bf_[nf] = *reinterpret_cast<const bf16x8*>(                     \
                    bs_ + col_ * 128 + (((kk * 4 + kg) ^ (col_ & 7)) * 16));    \
            }                                                                   \
            _Pragma("unroll")                                                   \
            for (int mf = 0; mf < 4; ++mf)                                      \
                _Pragma("unroll")                                               \
                for (int nf = 0; nf < 4; ++nf)                                  \
                    acc[mf][nf] = __builtin_amdgcn_mfma_f32_16x16x32_bf16(      \
                        F[mf * 2 + kk], bf_[nf], acc[mf][nf], 0, 0, 0);         \
        }                                                                       \
    } while (0)

    // prologue
    LOADB2(0, rb0);
    LOADB2(1, rb1);
    LOADA2(0, aF0);
    STOREB2(0, rb0);
    lgkm_bar();

    for (int j = 0; j < NS / 2; ++j) {
        const int ks = 2 * j;
        {
            const int ka = (ks + 1 < NS) ? ks + 1 : NS - 1;
            const int kb = (ks + 2 < NS) ? ks + 2 : NS - 1;
            LOADA2(ka, aF1);
            LOADB2(kb, rb0);
        }
        MFMAPH2(0, aF0);
        STOREB2(1, rb1);
        lgkm_bar();
        {
            const int ka = (ks + 2 < NS) ? ks + 2 : NS - 1;
            const int kb = (ks + 3 < NS) ? ks + 3 : NS - 1;
            LOADA2(ka, aF0);
            LOADB2(kb, rb1);
        }
        MFMAPH2(1, aF1);
        STOREB2(0, rb0);
        lgkm_bar();
    }
#undef LOADB2
#undef STOREB2
#undef LOADA2
#undef MFMAPH2

    // waveset reduce: ws1 partials -> LDS (smem reused), ws0 adds and
    // atomicAdds the kh-partial into the zeroed output.
    lgkm_bar();                                // all staging reads complete
    if (ws == 1) {
#pragma unroll
        for (int mf = 0; mf < 4; ++mf)
#pragma unroll
            for (int nf = 0; nf < 4; ++nf)
#pragma unroll
                for (int r = 0; r < 4; ++r) {
                    const int row = wr * 64 + mf * 16 + kg * 4 + r;
                    const int col = nf * 16 + lrow;
                    red[row * 64 + col] = acc[mf][nf][r];
                }
    }
    lgkm_bar();
    if (ws == 0) {
#pragma unroll
        for (int mf = 0; mf < 4; ++mf)
#pragma unroll
            for (int nf = 0; nf < 4; ++nf)
#pragma unroll
                for (int r = 0; r < 4; ++r) {
                    const int row = wr * 64 + mf * 16 + kg * 4 + r;
                    const int col = nf * 16 + lrow;
                    atomicAdd(&out[(size_t)(m0 + row) * HD + n0 + col],
                              acc[mf][nf][r] + red[row * 64 + col]);
                }
    }
}

// --------------------------------------------------------------- launch -----
extern "C" void kernel_launch(void* const* d_in, const int* in_sizes, int n_in,
                              void* d_out, int out_size, void* d_ws, size_t ws_size,
                              hipStream_t stream) {
    const float* x   = (const float*)d_in[0];
    const float* rw  = (const float*)d_in[1];
    const float* gup = (const float*)d_in[2];
    const float* dwn = (const float*)d_in[3];
    const float* sgw = (const float*)d_in[4];
    const float* suw = (const float*)d_in[5];
    const float* sdw = (const float*)d_in[6];

    float* out     = (float*)d_out;
    float* scoresT = out + (size_t)T_TOK * HD;

    char* ws   = (char*)d_ws;
    u16* xbf   = (u16*)ws;                                    // 4 MB
    u16* xsbf  = (u16*)(ws + (size_t)T_TOK * HD * 2);         // 4 MB
    u16* h2    = (u16*)(ws + (size_t)2 * T_TOK * HD * 2);     // 32 MB

    // zero the final-output region: G2 accumulates kh-partials atomically
    (void)hipMemsetAsync(out, 0, (size_t)T_TOK * HD * sizeof(float), stream);

    k_router<<<T_TOK, 256, 0, stream>>>(x, rw, scoresT, xbf, xsbf);
    k_gemm1<<<(T_TOK / 256) * (NN2 / 128), 512, 0, stream>>>(xbf, xsbf, sgw, suw, gup, h2);
    k_gemm2<<<256, 512, 0, stream>>>(h2, sdw, dwn, out);
}

// Round 18
// 211.882 us; speedup vs baseline: 1.0310x; 1.0310x over previous
//
#include <hip/hip_runtime.h>
#include <hip/hip_bf16.h>
#include <stdint.h>

#define T_TOK 2048
#define HD    1024
#define ID    4096
#define NE    8
#define NN2   8192   // 2*ID
#define CHUNK 256    // T_TOK / NE

typedef short          bf16x8 __attribute__((ext_vector_type(8)));
typedef float          f32x4  __attribute__((ext_vector_type(4)));
typedef unsigned short u16;

__device__ __forceinline__ u16 f2bf(float f) {
    return __builtin_bit_cast(u16, __float2bfloat16(f));
}

// Barrier that does NOT drain vmcnt: LDS-ordering only (T3/T4 pattern).
__device__ __forceinline__ void lgkm_bar() {
    asm volatile("s_waitcnt lgkmcnt(0)" ::: "memory");
    __builtin_amdgcn_s_barrier();
}

// ---------------------------------------------------------------- router ----
__global__ __launch_bounds__(256) void k_router(
    const float* __restrict__ x, const float* __restrict__ rw,
    float* __restrict__ scoresT, u16* __restrict__ xbf, u16* __restrict__ xsbf)
{
    const int t   = blockIdx.x;
    const int tid = threadIdx.x;
    __shared__ float wred[NE][4];
    __shared__ float ssc;

    float4 xv = reinterpret_cast<const float4*>(x + (size_t)t * HD)[tid];
    float p[NE];
#pragma unroll
    for (int e = 0; e < NE; ++e) p[e] = 0.f;
    const float* wrow = rw + (size_t)tid * 4 * NE;
    float xj[4] = {xv.x, xv.y, xv.z, xv.w};
#pragma unroll
    for (int j = 0; j < 4; ++j)
#pragma unroll
        for (int e = 0; e < NE; ++e) p[e] += xj[j] * wrow[j * NE + e];

#pragma unroll
    for (int e = 0; e < NE; ++e) {
        float v = p[e];
#pragma unroll
        for (int o = 32; o > 0; o >>= 1) v += __shfl_down(v, o, 64);
        if ((tid & 63) == 0) wred[e][tid >> 6] = v;
    }
    __syncthreads();
    if (tid == 0) {
        float mx = -3.4e38f; int am = 0;
        float lg[NE];
#pragma unroll
        for (int e = 0; e < NE; ++e) {
            lg[e] = wred[e][0] + wred[e][1] + wred[e][2] + wred[e][3];
            if (lg[e] > mx) { mx = lg[e]; am = e; }
        }
        float sc = 1.f / (1.f + __expf(-mx));
        ssc = sc;
#pragma unroll
        for (int e = 0; e < NE; ++e)
            scoresT[(size_t)e * T_TOK + t] = (e == am) ? sc : 0.f;
    }
    __syncthreads();
    const float sc = ssc;
    ushort4 a, b;
    a.x = f2bf(xj[0]); a.y = f2bf(xj[1]); a.z = f2bf(xj[2]); a.w = f2bf(xj[3]);
    b.x = f2bf(xj[0] * sc); b.y = f2bf(xj[1] * sc); b.z = f2bf(xj[2] * sc); b.w = f2bf(xj[3] * sc);
    reinterpret_cast<ushort4*>(xbf  + (size_t)t * HD)[tid] = a;
    reinterpret_cast<ushort4*>(xsbf + (size_t)t * HD)[tid] = b;
}

// ------------------------------------------------------------------- G1 -----
// Session-best configuration (r10/r11/r16, ~110 us): BM=256, BN=128, BK=32,
// 8 waves (4x2), wave 64x64. A direct from global (dual-bank depth-1
// prefetch), B fp32 reg-staged depth-2 into dbuf LDS, NON-TEMPORAL B loads
// (stream-once weights stay out of L1/L2; A slab stays hot), lgkm-only
// barriers so prefetches ride across steps.
__global__ __launch_bounds__(512, 2) void k_gemm1(
    const u16* __restrict__ xbf, const u16* __restrict__ xsbf,
    const float* __restrict__ sgw, const float* __restrict__ suw,
    const float* __restrict__ gup, u16* __restrict__ h2)
{
    constexpr int BM = 256, BN = 128, BK = 32, NS = HD / BK;   // 32 steps
    const int d = blockIdx.x;
    int mt, nt;
    if (d < 256) { const int r = d & 7, q = d >> 3; nt = r + 8 * (q & 3); mt = q >> 2; }
    else         { const int e = d - 256;           mt = e & 7; nt = 32 + (e >> 3); }
    const int m0 = mt * BM, n0 = nt * BN;

    const u16* A; const float* Bg; const float* Bu; int ldb;
    if (n0 < ID) { A = xbf; Bg = sgw + n0; Bu = suw + n0; ldb = ID; }
    else {
        A = xsbf;
        Bg = gup + (size_t)mt * HD * NN2 + (n0 - ID);
        Bu = Bg + ID;
        ldb = NN2;
    }

    __shared__ u16 Bgs[2][BN * BK];
    __shared__ u16 Bus[2][BN * BK];

    const int tid  = threadIdx.x;
    const int lane = tid & 63, wid = tid >> 6;
    const int wr = wid >> 1, wc = wid & 1;        // 4 x 2 wave grid
    const int lrow = lane & 15, kg = lane >> 4;

    f32x4 accg[4][4], accu[4][4];
#pragma unroll
    for (int i = 0; i < 4; ++i)
#pragma unroll
        for (int j = 0; j < 4; ++j)
#pragma unroll
            for (int r = 0; r < 4; ++r) { accg[i][j][r] = 0.f; accu[i][j][r] = 0.f; }

    const int bcol = tid & 127, bkh = tid >> 7;   // B: 128 cols x 4 k-octets
    const int bsw  = (bcol >> 1) & 3;
    const u16* aBase = A + (size_t)(m0 + wr * 64 + lrow) * HD + kg * 8;

    float g0[8], u0[8], g1[8], u1[8];
    bf16x8 aF0[4], aF1[4];

#define LOADB(ks, rg, ru) do {                                                  \
        const float* bgp_ = Bg + (size_t)((ks) * BK + bkh * 8) * ldb + bcol;    \
        const float* bup_ = Bu + (size_t)((ks) * BK + bkh * 8) * ldb + bcol;    \
        _Pragma("unroll")                                                       \
        for (int j = 0; j < 8; ++j) {                                           \
            rg[j] = __builtin_nontemporal_load(bgp_ + (size_t)j * ldb);         \
            ru[j] = __builtin_nontemporal_load(bup_ + (size_t)j * ldb);         \
        }                                                                       \
    } while (0)

#define STOREB(b, rg, ru) do {                                                  \
        bf16x8 wg_, wu_;                                                        \
        _Pragma("unroll")                                                       \
        for (int j = 0; j < 8; ++j) { wg_[j] = (short)f2bf(rg[j]);              \
                                      wu_[j] = (short)f2bf(ru[j]); }            \
        *reinterpret_cast<bf16x8*>(reinterpret_cast<char*>(Bgs[b])              \
            + bcol * 64 + ((bkh ^ bsw) * 16)) = wg_;                            \
        *reinterpret_cast<bf16x8*>(reinterpret_cast<char*>(Bus[b])              \
            + bcol * 64 + ((bkh ^ bsw) * 16)) = wu_;                            \
    } while (0)

#define LOADA(ks, F) do {                                                       \
        _Pragma("unroll")                                                       \
        for (int mf = 0; mf < 4; ++mf)                                          \
            F[mf] = *reinterpret_cast<const bf16x8*>(                           \
                aBase + (size_t)mf * 16 * HD + (ks) * BK);                      \
    } while (0)

#define MFMAPH(b, F) do {                                                       \
        const char* gs_ = (const char*)Bgs[b];                                  \
        const char* us_ = (const char*)Bus[b];                                  \
        bf16x8 bgf_[4], buf_[4];                                                \
        _Pragma("unroll")                                                       \
        for (int nf = 0; nf < 4; ++nf) {                                        \
            const int col_ = wc * 64 + nf * 16 + lrow;                          \
            const int so_  = col_ * 64 + ((kg ^ ((col_ >> 1) & 3)) * 16);       \
            bgf_[nf] = *reinterpret_cast<const bf16x8*>(gs_ + so_);             \
            buf_[nf] = *reinterpret_cast<const bf16x8*>(us_ + so_);             \
        }                                                                       \
        _Pragma("unroll")                                                       \
        for (int mf = 0; mf < 4; ++mf)                                          \
            _Pragma("unroll")                                                   \
            for (int nf = 0; nf < 4; ++nf) {                                    \
                accg[mf][nf] = __builtin_amdgcn_mfma_f32_16x16x32_bf16(         \
                    F[mf], bgf_[nf], accg[mf][nf], 0, 0, 0);                    \
                accu[mf][nf] = __builtin_amdgcn_mfma_f32_16x16x32_bf16(         \
                    F[mf], buf_[nf], accu[mf][nf], 0, 0, 0);                    \
            }                                                                   \
    } while (0)

    // prologue
    LOADB(0, g0, u0);
    LOADB(1, g1, u1);
    LOADA(0, aF0);
    STOREB(0, g0, u0);
    lgkm_bar();

    for (int j = 0; j < NS / 2; ++j) {
        const int ks = 2 * j;
        {
            const int ka = (ks + 1 < NS) ? ks + 1 : NS - 1;
            const int kb = (ks + 2 < NS) ? ks + 2 : NS - 1;
            LOADA(ka, aF1);
            LOADB(kb, g0, u0);
        }
        MFMAPH(0, aF0);
        STOREB(1, g1, u1);
        lgkm_bar();
        {
            const int ka = (ks + 2 < NS) ? ks + 2 : NS - 1;
            const int kb = (ks + 3 < NS) ? ks + 3 : NS - 1;
            LOADA(ka, aF0);
            LOADB(kb, g1, u1);
        }
        MFMAPH(1, aF1);
        STOREB(0, g0, u0);
        lgkm_bar();
    }
#undef LOADB
#undef STOREB
#undef LOADA
#undef MFMAPH

    // SwiGLU epilogue -> bf16 H2
#pragma unroll
    for (int mf = 0; mf < 4; ++mf)
#pragma unroll
        for (int nf = 0; nf < 4; ++nf) {
            const int col = n0 + wc * 64 + nf * 16 + lrow;
#pragma unroll
            for (int r = 0; r < 4; ++r) {
                const int row = m0 + wr * 64 + mf * 16 + kg * 4 + r;
                const float g = accg[mf][nf][r];
                const float u = accu[mf][nf][r];
                const float h = (g / (1.f + __expf(-g))) * u;
                h2[(size_t)row * NN2 + col] = f2bf(h);
            }
        }
}

// ------------------------------------------------------------------- G2 -----
// Session-best configuration (r11/r16, ~92 us): BM=256 (=CHUNK), BN=64,
// K SPLIT ACROSS BLOCKS: kh=0 -> shared_down K=[0,4096); kh=1 -> dwn[mt].
// Grid 256 = 8 mt x 16 nt x 2 kh; mt pinned to XCD (h2 slab L2-hot, 16x
// reuse). 2 wavesets x 4 waves over K-quarters (BK=64, NS=32), depth-2 B,
// dual-bank A, lgkm barriers; LDS waveset-reduce; kh-partials combined by
// atomicAdd onto zeroed out (2 commutative addends/address).
__global__ __launch_bounds__(512, 1) void k_gemm2(
    const u16* __restrict__ h2, const float* __restrict__ sdw,
    const float* __restrict__ dwn, float* __restrict__ out)
{
    constexpr int BM = 256, BN = 64, BK = 64, NS = 2048 / BK;  // 32 steps/waveset
    const int d   = blockIdx.x;               // 256 blocks
    const int mt  = d & 7;                    // = XCD
    const int q   = d >> 3;
    const int kh  = q & 1;                    // K-half: 0=sdw, 1=dwn[mt]
    const int nt  = q >> 1;                   // 0..15
    const int m0 = mt * BM, n0 = nt * BN;

    const int tid = threadIdx.x;
    const int ws  = tid >> 8;                 // waveset 0/1
    const int wt  = tid & 255;
    const int lane = wt & 63, wid4 = wt >> 6; // 4 waves per waveset
    const int wr = wid4;                      // 4x1 wave grid, 64 rows each
    const int lrow = lane & 15, kg = lane >> 4;

    __shared__ char smem[65536];              // 32 KB staging, reused as reduce
    u16*   BsBase = (u16*)smem;               // [set][buf][BN*BK]
    float* red    = (float*)smem;             // 256 x 64 f32

    f32x4 acc[4][4];
#pragma unroll
    for (int i = 0; i < 4; ++i)
#pragma unroll
        for (int j = 0; j < 4; ++j)
#pragma unroll
            for (int r = 0; r < 4; ++r) acc[i][j][r] = 0.f;

    const float* Bbase = kh ? (dwn + (size_t)mt * ID * HD + (size_t)(ws * 2048) * HD)
                            : (sdw + (size_t)(ws * 2048) * HD);
    const u16* aBase = h2 + (size_t)(m0 + wr * 64 + lrow) * NN2
                          + (size_t)kh * ID + (size_t)ws * 2048 + kg * 8;

    const int bcol = wt & 63, bkq = wt >> 6;  // 64 cols x 4 k-16-groups
    const int bsw  = bcol & 7;

    float rb0[16], rb1[16];
    bf16x8 aF0[8], aF1[8];

#define LOADB2(ks, rb) do {                                                     \
        const float* bb_ = Bbase + (size_t)((ks) * BK + bkq * 16) * HD + n0 + bcol; \
        _Pragma("unroll")                                                       \
        for (int j = 0; j < 16; ++j) rb[j] = bb_[(size_t)j * HD];               \
    } while (0)

#define STOREB2(b, rb) do {                                                     \
        bf16x8 w0_, w1_;                                                        \
        _Pragma("unroll")                                                       \
        for (int j = 0; j < 8; ++j) { w0_[j] = (short)f2bf(rb[j]);              \
                                      w1_[j] = (short)f2bf(rb[8 + j]); }        \
        char* bs_ = (char*)(BsBase + (size_t)(ws * 2 + (b)) * BN * BK);         \
        *reinterpret_cast<bf16x8*>(bs_ + bcol * 128 + (((bkq * 2 + 0) ^ bsw) * 16)) = w0_; \
        *reinterpret_cast<bf16x8*>(bs_ + bcol * 128 + (((bkq * 2 + 1) ^ bsw) * 16)) = w1_; \
    } while (0)

#define LOADA2(ks, F) do {                                                      \
        _Pragma("unroll")                                                       \
        for (int mf = 0; mf < 4; ++mf)                                          \
            _Pragma("unroll")                                                   \
            for (int kk = 0; kk < 2; ++kk)                                      \
                F[mf * 2 + kk] = *reinterpret_cast<const bf16x8*>(              \
                    aBase + (size_t)mf * 16 * NN2 + (ks) * BK + kk * 32);       \
    } while (0)

#define MFMAPH2(b, F) do {                                                      \
        const char* bs_ = (const char*)(BsBase + (size_t)(ws * 2 + (b)) * BN * BK); \
        _Pragma("unroll")                                                       \
        for (int kk = 0; kk < 2; ++kk) {                                        \
            bf16x8 bf_[4];                                                      \
            _Pragma("unroll")                                                   \
            for (int nf = 0; nf < 4; ++nf) {                                    \
                const int col_ = nf * 16 + lrow;                                \
                bf_[nf] = *reinterpret_cast<const bf16x8*>(                     \
                    bs_ + col_ * 128 + (((kk * 4 + kg) ^ (col_ & 7)) * 16));    \
            }                                                                   \
            _Pragma("unroll")                                                   \
            for (int mf = 0; mf < 4; ++mf)                                      \
                _Pragma("unroll")                                               \
                for (int nf = 0; nf < 4; ++nf)                                  \
                    acc[mf][nf] = __builtin_amdgcn_mfma_f32_16x16x32_bf16(      \
                        F[mf * 2 + kk], bf_[nf], acc[mf][nf], 0, 0, 0);         \
        }                                                                       \
    } while (0)

    // prologue
    LOADB2(0, rb0);
    LOADB2(1, rb1);
    LOADA2(0, aF0);
    STOREB2(0, rb0);
    lgkm_bar();

    for (int j = 0; j < NS / 2; ++j) {
        const int ks = 2 * j;
        {
            const int ka = (ks + 1 < NS) ? ks + 1 : NS - 1;
            const int kb = (ks + 2 < NS) ? ks + 2 : NS - 1;
            LOADA2(ka, aF1);
            LOADB2(kb, rb0);
        }
        MFMAPH2(0, aF0);
        STOREB2(1, rb1);
        lgkm_bar();
        {
            const int ka = (ks + 2 < NS) ? ks + 2 : NS - 1;
            const int kb = (ks + 3 < NS) ? ks + 3 : NS - 1;
            LOADA2(ka, aF0);
            LOADB2(kb, rb1);
        }
        MFMAPH2(1, aF1);
        STOREB2(0, rb0);
        lgkm_bar();
    }
#undef LOADB2
#undef STOREB2
#undef LOADA2
#undef MFMAPH2

    // waveset reduce: ws1 partials -> LDS (smem reused), ws0 adds and
    // atomicAdds the kh-partial into the zeroed output.
    lgkm_bar();                                // all staging reads complete
    if (ws == 1) {
#pragma unroll
        for (int mf = 0; mf < 4; ++mf)
#pragma unroll
            for (int nf = 0; nf < 4; ++nf)
#pragma unroll
                for (int r = 0; r < 4; ++r) {
                    const int row = wr * 64 + mf * 16 + kg * 4 + r;
                    const int col = nf * 16 + lrow;
                    red[row * 64 + col] = acc[mf][nf][r];
                }
    }
    lgkm_bar();
    if (ws == 0) {
#pragma unroll
        for (int mf = 0; mf < 4; ++mf)
#pragma unroll
            for (int nf = 0; nf < 4; ++nf)
#pragma unroll
                for (int r = 0; r < 4; ++r) {
                    const int row = wr * 64 + mf * 16 + kg * 4 + r;
                    const int col = nf * 16 + lrow;
                    atomicAdd(&out[(size_t)(m0 + row) * HD + n0 + col],
                              acc[mf][nf][r] + red[row * 64 + col]);
                }
    }
}

// --------------------------------------------------------------- launch -----
extern "C" void kernel_launch(void* const* d_in, const int* in_sizes, int n_in,
                              void* d_out, int out_size, void* d_ws, size_t ws_size,
                              hipStream_t stream) {
    const float* x   = (const float*)d_in[0];
    const float* rw  = (const float*)d_in[1];
    const float* gup = (const float*)d_in[2];
    const float* dwn = (const float*)d_in[3];
    const float* sgw = (const float*)d_in[4];
    const float* suw = (const float*)d_in[5];
    const float* sdw = (const float*)d_in[6];

    float* out     = (float*)d_out;
    float* scoresT = out + (size_t)T_TOK * HD;

    char* ws   = (char*)d_ws;
    u16* xbf   = (u16*)ws;                                    // 4 MB
    u16* xsbf  = (u16*)(ws + (size_t)T_TOK * HD * 2);         // 4 MB
    u16* h2    = (u16*)(ws + (size_t)2 * T_TOK * HD * 2);     // 32 MB

    // zero the final-output region: G2 accumulates kh-partials atomically
    (void)hipMemsetAsync(out, 0, (size_t)T_TOK * HD * sizeof(float), stream);

    k_router<<<T_TOK, 256, 0, stream>>>(x, rw, scoresT, xbf, xsbf);
    k_gemm1<<<(T_TOK / 256) * (NN2 / 128), 512, 0, stream>>>(xbf, xsbf, sgw, suw, gup, h2);
    k_gemm2<<<256, 512, 0, stream>>>(h2, sdw, dwn, out);
}